// Round 1
// baseline (622.043 us; speedup 1.0000x reference)
//
#include <hip/hip_runtime.h>

#define LDT 68  // padded row stride (floats) for 64x64 LDS tiles: 68*4B=272B, 16B-aligned, odd bank stride

__device__ __forceinline__ float tanh_fast(float v) {
    // tanh(v) = 1 - 2/(exp(2v)+1); exact at +/-inf, rel err ~1e-6
    float e = __expf(2.0f * v);
    float d = e + 1.0f;
#if __has_builtin(__builtin_amdgcn_rcpf)
    float r = __builtin_amdgcn_rcpf(d);
#else
    float r = 1.0f / d;
#endif
    return 1.0f - 2.0f * r;
}

// ---------------------------------------------------------------------------
// Precompute: M = (I + 0.02*A)^50 via square-and-multiply (7 matmuls), then
// W1p = M @ W1  -> d_ws  (64 x 256 f32, row-major)
// Single block, 256 threads. fp32 throughout.
// ---------------------------------------------------------------------------
__global__ __launch_bounds__(256) void ode_precompute(
        const float* __restrict__ A, const float* __restrict__ W1,
        float* __restrict__ w1p) {
    __shared__ float Ts[64 * LDT];
    __shared__ float Za[64 * LDT];
    __shared__ float Zb[64 * LDT];
    const int t = threadIdx.x;

    for (int i = t; i < 4096; i += 256) {
        int r = i >> 6, c = i & 63;
        float v = 0.02f * A[i] + ((r == c) ? 1.0f : 0.0f);
        Ts[r * LDT + c] = v;
        Za[r * LDT + c] = v;  // acc = T
    }
    __syncthreads();

    const int r0 = (t >> 4) * 4;  // 4x4 output tile per thread
    const int c0 = (t & 15) * 4;

    auto mm = [&](const float* X, const float* Y, float* Z) {
        // Z = X @ Y (all 64x64 in LDS, stride LDT). Z != X, Z != Y.
        float acc[4][4];
        #pragma unroll
        for (int i = 0; i < 4; i++)
            #pragma unroll
            for (int j = 0; j < 4; j++) acc[i][j] = 0.0f;
        #pragma unroll 8
        for (int k = 0; k < 64; k++) {
            float a0 = X[(r0 + 0) * LDT + k];
            float a1 = X[(r0 + 1) * LDT + k];
            float a2 = X[(r0 + 2) * LDT + k];
            float a3 = X[(r0 + 3) * LDT + k];
            const float4 b = *(const float4*)(Y + k * LDT + c0);
            acc[0][0] = fmaf(a0, b.x, acc[0][0]); acc[0][1] = fmaf(a0, b.y, acc[0][1]);
            acc[0][2] = fmaf(a0, b.z, acc[0][2]); acc[0][3] = fmaf(a0, b.w, acc[0][3]);
            acc[1][0] = fmaf(a1, b.x, acc[1][0]); acc[1][1] = fmaf(a1, b.y, acc[1][1]);
            acc[1][2] = fmaf(a1, b.z, acc[1][2]); acc[1][3] = fmaf(a1, b.w, acc[1][3]);
            acc[2][0] = fmaf(a2, b.x, acc[2][0]); acc[2][1] = fmaf(a2, b.y, acc[2][1]);
            acc[2][2] = fmaf(a2, b.z, acc[2][2]); acc[2][3] = fmaf(a2, b.w, acc[2][3]);
            acc[3][0] = fmaf(a3, b.x, acc[3][0]); acc[3][1] = fmaf(a3, b.y, acc[3][1]);
            acc[3][2] = fmaf(a3, b.z, acc[3][2]); acc[3][3] = fmaf(a3, b.w, acc[3][3]);
        }
        // writes target a buffer no one reads this phase; barrier after
        #pragma unroll
        for (int i = 0; i < 4; i++)
            *(float4*)(Z + (r0 + i) * LDT + c0) =
                make_float4(acc[i][0], acc[i][1], acc[i][2], acc[i][3]);
        __syncthreads();
    };

    // 50 = 0b110010 -> sq, *T, sq, sq, sq, *T, sq
    mm(Za, Za, Zb);  // T^2
    mm(Zb, Ts, Za);  // T^3
    mm(Za, Za, Zb);  // T^6
    mm(Zb, Zb, Za);  // T^12
    mm(Za, Za, Zb);  // T^24
    mm(Zb, Ts, Za);  // T^25
    mm(Za, Za, Zb);  // T^50  -> Zb
    // W1p = Zb @ W1 : per-thread 4 rows x 16 cols
    {
        const int rp = (t >> 4) * 4;
        const int cp = (t & 15) * 16;
        float acc[4][16];
        #pragma unroll
        for (int i = 0; i < 4; i++)
            #pragma unroll
            for (int j = 0; j < 16; j++) acc[i][j] = 0.0f;
        #pragma unroll 4
        for (int k = 0; k < 64; k++) {
            float a0 = Zb[(rp + 0) * LDT + k];
            float a1 = Zb[(rp + 1) * LDT + k];
            float a2 = Zb[(rp + 2) * LDT + k];
            float a3 = Zb[(rp + 3) * LDT + k];
            const float4* wg = (const float4*)(W1 + k * 256 + cp);
            float4 q0 = wg[0], q1 = wg[1], q2 = wg[2], q3 = wg[3];
            float aa[4] = {a0, a1, a2, a3};
            #pragma unroll
            for (int i = 0; i < 4; i++) {
                acc[i][0]  = fmaf(aa[i], q0.x, acc[i][0]);
                acc[i][1]  = fmaf(aa[i], q0.y, acc[i][1]);
                acc[i][2]  = fmaf(aa[i], q0.z, acc[i][2]);
                acc[i][3]  = fmaf(aa[i], q0.w, acc[i][3]);
                acc[i][4]  = fmaf(aa[i], q1.x, acc[i][4]);
                acc[i][5]  = fmaf(aa[i], q1.y, acc[i][5]);
                acc[i][6]  = fmaf(aa[i], q1.z, acc[i][6]);
                acc[i][7]  = fmaf(aa[i], q1.w, acc[i][7]);
                acc[i][8]  = fmaf(aa[i], q2.x, acc[i][8]);
                acc[i][9]  = fmaf(aa[i], q2.y, acc[i][9]);
                acc[i][10] = fmaf(aa[i], q2.z, acc[i][10]);
                acc[i][11] = fmaf(aa[i], q2.w, acc[i][11]);
                acc[i][12] = fmaf(aa[i], q3.x, acc[i][12]);
                acc[i][13] = fmaf(aa[i], q3.y, acc[i][13]);
                acc[i][14] = fmaf(aa[i], q3.z, acc[i][14]);
                acc[i][15] = fmaf(aa[i], q3.w, acc[i][15]);
            }
        }
        #pragma unroll
        for (int i = 0; i < 4; i++)
            #pragma unroll
            for (int jq = 0; jq < 4; jq++)
                *(float4*)(w1p + (rp + i) * 256 + cp + jq * 4) =
                    make_float4(acc[i][4 * jq + 0], acc[i][4 * jq + 1],
                                acc[i][4 * jq + 2], acc[i][4 * jq + 3]);
    }
}

// ---------------------------------------------------------------------------
// Main fused kernel: out = tanh(x @ W1p + b1) @ W2 + b2
// 512 threads/block, 1 row per thread. W1p staged in LDS (64KB, broadcast
// reads); W2 (16KB) read from global -> L1-resident, uniform addresses.
// ---------------------------------------------------------------------------
__global__ __launch_bounds__(512) void ode_main(
        const float* __restrict__ x, const float* __restrict__ w1p,
        const float* __restrict__ b1, const float* __restrict__ W2,
        const float* __restrict__ b2, float* __restrict__ out, int B) {
    __shared__ float w1s[64 * 256];
    __shared__ float b1s[256];
    __shared__ float b2s[16];
    const int t = threadIdx.x;
    {
        const float4* src = (const float4*)w1p;
        float4* dst = (float4*)w1s;
        #pragma unroll
        for (int i = 0; i < 8; i++) dst[t + 512 * i] = src[t + 512 * i];
        if (t < 64) ((float4*)b1s)[t] = ((const float4*)b1)[t];
        if (t < 4) ((float4*)b2s)[t] = ((const float4*)b2)[t];
    }
    __syncthreads();
    const int row = blockIdx.x * 512 + t;
    if (row >= B) return;

    float4 xr[16];
    {
        const float4* xp = (const float4*)(x + (size_t)row * 64);
        #pragma unroll
        for (int i = 0; i < 16; i++) xr[i] = xp[i];
    }
    float oacc[16];
    #pragma unroll
    for (int o = 0; o < 16; o++) oacc[o] = 0.0f;

    for (int nb = 0; nb < 32; nb++) {
        const int n0 = nb * 8;
        float acc[8];
        #pragma unroll
        for (int j = 0; j < 8; j++) acc[j] = b1s[n0 + j];
        #pragma unroll
        for (int k = 0; k < 64; k++) {
            const float xk = ((const float*)xr)[k];
            const float4 w0 = *(const float4*)(w1s + (k << 8) + n0);
            const float4 w1v = *(const float4*)(w1s + (k << 8) + n0 + 4);
            acc[0] = fmaf(xk, w0.x, acc[0]);
            acc[1] = fmaf(xk, w0.y, acc[1]);
            acc[2] = fmaf(xk, w0.z, acc[2]);
            acc[3] = fmaf(xk, w0.w, acc[3]);
            acc[4] = fmaf(xk, w1v.x, acc[4]);
            acc[5] = fmaf(xk, w1v.y, acc[5]);
            acc[6] = fmaf(xk, w1v.z, acc[6]);
            acc[7] = fmaf(xk, w1v.w, acc[7]);
        }
        #pragma unroll
        for (int j = 0; j < 8; j++) {
            const float hn = tanh_fast(acc[j]);
            const float4* w2r = (const float4*)(W2 + ((n0 + j) << 4));
            const float4 a = w2r[0], b = w2r[1], c = w2r[2], d = w2r[3];
            oacc[0]  = fmaf(hn, a.x, oacc[0]);
            oacc[1]  = fmaf(hn, a.y, oacc[1]);
            oacc[2]  = fmaf(hn, a.z, oacc[2]);
            oacc[3]  = fmaf(hn, a.w, oacc[3]);
            oacc[4]  = fmaf(hn, b.x, oacc[4]);
            oacc[5]  = fmaf(hn, b.y, oacc[5]);
            oacc[6]  = fmaf(hn, b.z, oacc[6]);
            oacc[7]  = fmaf(hn, b.w, oacc[7]);
            oacc[8]  = fmaf(hn, c.x, oacc[8]);
            oacc[9]  = fmaf(hn, c.y, oacc[9]);
            oacc[10] = fmaf(hn, c.z, oacc[10]);
            oacc[11] = fmaf(hn, c.w, oacc[11]);
            oacc[12] = fmaf(hn, d.x, oacc[12]);
            oacc[13] = fmaf(hn, d.y, oacc[13]);
            oacc[14] = fmaf(hn, d.z, oacc[14]);
            oacc[15] = fmaf(hn, d.w, oacc[15]);
        }
    }
    float4* op = (float4*)(out + (size_t)row * 16);
    #pragma unroll
    for (int q = 0; q < 4; q++)
        op[q] = make_float4(oacc[4 * q + 0] + b2s[4 * q + 0],
                            oacc[4 * q + 1] + b2s[4 * q + 1],
                            oacc[4 * q + 2] + b2s[4 * q + 2],
                            oacc[4 * q + 3] + b2s[4 * q + 3]);
}

extern "C" void kernel_launch(void* const* d_in, const int* in_sizes, int n_in,
                              void* d_out, int out_size, void* d_ws, size_t ws_size,
                              hipStream_t stream) {
    const float* x  = (const float*)d_in[0];
    const float* A  = (const float*)d_in[1];
    const float* W1 = (const float*)d_in[2];
    const float* b1 = (const float*)d_in[3];
    const float* W2 = (const float*)d_in[4];
    const float* b2 = (const float*)d_in[5];
    float* out = (float*)d_out;
    float* w1p = (float*)d_ws;  // 64*256 f32 = 64KB scratch

    const int B = in_sizes[0] / 64;

    ode_precompute<<<1, 256, 0, stream>>>(A, W1, w1p);
    const int grid = (B + 511) / 512;
    ode_main<<<grid, 512, 0, stream>>>(x, w1p, b1, W2, b2, out, B);
}

// Round 2
// 256.834 us; speedup vs baseline: 2.4220x; 2.4220x over previous
//
#include <hip/hip_runtime.h>

typedef float f32x4 __attribute__((ext_vector_type(4)));
typedef __bf16 bf16x8 __attribute__((ext_vector_type(8)));

__device__ __forceinline__ unsigned short bf16_rne(float f) {
    unsigned u = __builtin_bit_cast(unsigned, f);
    u += 0x7FFFu + ((u >> 16) & 1u);
    return (unsigned short)(u >> 16);
}
__device__ __forceinline__ float bf16_to_f(unsigned short h) {
    return __builtin_bit_cast(float, ((unsigned)h) << 16);
}
__device__ __forceinline__ float tanh_fast(float v) {
    float e = __expf(2.0f * v);
    float r = 1.0f / (e + 1.0f);
    return 1.0f - 2.0f * r;
}

#define LDT 68

// ---------------------------------------------------------------------------
// Precompute: T = I + 0.02A; M = T^50 (7 LDS matmuls, fp32); then write
//   ws[0      .. 16383] : W1p = M@W1 as GEMM1 B-fragments (bf16)
//                         layout ((nt*2+kt)*64 + lane)*8 + j,
//                         value = W1p[32kt + 8*(lane>>4) + j][16nt + (lane&15)]
//   ws[16384 .. 20479] : W2 as GEMM2 B-fragments (bf16) under k-permutation
//                         k' = 64pp + 4c + nt4  <->  col = 64pp + 16nt4 + c
// 1 block, 1024 threads.
// ---------------------------------------------------------------------------
__global__ __launch_bounds__(1024) void ode_precompute(
        const float* __restrict__ A, const float* __restrict__ W1,
        const float* __restrict__ W2, unsigned short* __restrict__ ws) {
    __shared__ float Ts[64 * LDT];
    __shared__ float Za[64 * LDT];
    __shared__ float Zb[64 * LDT];
    const int t = threadIdx.x;

    for (int i = t; i < 4096; i += 1024) {
        int r = i >> 6, c = i & 63;
        float v = 0.02f * A[i] + ((r == c) ? 1.0f : 0.0f);
        Ts[r * LDT + c] = v;
        Za[r * LDT + c] = v;
    }
    __syncthreads();

    const int r0 = (t >> 5) * 2;
    const int c0 = (t & 31) * 2;
    auto mm = [&](const float* X, const float* Y, float* Z) {
        float a00 = 0, a01 = 0, a10 = 0, a11 = 0;
        #pragma unroll 8
        for (int k = 0; k < 64; k++) {
            float x0 = X[r0 * LDT + k], x1 = X[(r0 + 1) * LDT + k];
            float y0 = Y[k * LDT + c0], y1 = Y[k * LDT + c0 + 1];
            a00 = fmaf(x0, y0, a00); a01 = fmaf(x0, y1, a01);
            a10 = fmaf(x1, y0, a10); a11 = fmaf(x1, y1, a11);
        }
        Z[r0 * LDT + c0] = a00;       Z[r0 * LDT + c0 + 1] = a01;
        Z[(r0 + 1) * LDT + c0] = a10; Z[(r0 + 1) * LDT + c0 + 1] = a11;
        __syncthreads();
    };
    // 50 = 0b110010 -> sq, *T, sq, sq, sq, *T, sq  (result in Zb)
    mm(Za, Za, Zb); mm(Zb, Ts, Za); mm(Za, Za, Zb); mm(Zb, Zb, Za);
    mm(Za, Za, Zb); mm(Zb, Ts, Za); mm(Za, Za, Zb);

    // W1p row k = t>>4; columns n = (t&15) + 16*j, j = 0..15
    {
        const int k = t >> 4;
        const int c = t & 15;
        float acc[16];
        #pragma unroll
        for (int j = 0; j < 16; j++) acc[j] = 0.0f;
        const float* trow = Zb + k * LDT;
        for (int d = 0; d < 64; d++) {
            float a = trow[d];
            const float* wrow = W1 + d * 256 + c;
            #pragma unroll
            for (int j = 0; j < 16; j++) acc[j] = fmaf(a, wrow[16 * j], acc[j]);
        }
        const int kt = k >> 5, q = (k >> 3) & 3, jj = k & 7;
        #pragma unroll
        for (int j = 0; j < 16; j++)
            ws[(((j * 2 + kt) * 64) + q * 16 + c) * 8 + jj] = bf16_rne(acc[j]);
    }
    // W2 fragments (4096 elems, 4 per thread)
    #pragma unroll
    for (int e = 0; e < 4; e++) {
        int f = t * 4 + e;
        int kt2 = f >> 9, l = (f >> 3) & 63, j2 = f & 7;
        int kp = 32 * kt2 + 8 * (l >> 4) + j2;
        int row = 64 * (kp >> 6) + 16 * (kp & 3) + ((kp >> 2) & 15);
        ws[16384 + f] = bf16_rne(W2[row * 16 + (l & 15)]);
    }
}

// ---------------------------------------------------------------------------
// Main: out = tanh(x @ W1p + b1) @ W2 + b2, MFMA bf16, split-hi/lo x.
// 512 threads (8 waves), 32 rows/wave (2 strips of 16), 256 rows/block.
// h lives in a wave-private LDS chunk (row stride 36 u32 -> bank-balanced
// b64 writes and b128 reads). No main-loop barriers.
// ---------------------------------------------------------------------------
__global__ __launch_bounds__(512, 4) void ode_main(
        const float* __restrict__ x, const unsigned short* __restrict__ wsfrag,
        const float* __restrict__ b1, const float* __restrict__ b2,
        float* __restrict__ out, int B) {
    __shared__ unsigned short w1f[16384];  // 32KB
    __shared__ unsigned short w2f[4096];   // 8KB
    __shared__ float b1s[256];             // 1KB
    __shared__ unsigned hbuf[8 * 2 * 16 * 36];  // 36KB
    const int t = threadIdx.x;
    {
        const uint4* src = (const uint4*)wsfrag;  // 2560 uint4
        uint4* d1 = (uint4*)w1f;
        #pragma unroll
        for (int i = 0; i < 4; i++) d1[t + 512 * i] = src[t + 512 * i];
        ((uint4*)w2f)[t] = src[2048 + t];
        if (t < 64) ((float4*)b1s)[t] = ((const float4*)b1)[t];
    }
    __syncthreads();

    const int wid = t >> 6, lane = t & 63;
    const int q = lane >> 4, c = lane & 15;
    const long rowbase = (long)blockIdx.x * 256 + wid * 32;

    // ---- load x (2 strips x 2 ktiles x 8 floats), split into bf16 hi/lo frags
    uint4 xhi[2][2], xlo[2][2];
    #pragma unroll
    for (int s = 0; s < 2; s++) {
        long row = rowbase + 16 * s + c;
        const float* xp = x + ((row < B) ? row : 0) * 64;
        #pragma unroll
        for (int kt = 0; kt < 2; kt++) {
            float4 u0 = *(const float4*)(xp + kt * 32 + q * 8);
            float4 u1 = *(const float4*)(xp + kt * 32 + q * 8 + 4);
            float v[8] = {u0.x, u0.y, u0.z, u0.w, u1.x, u1.y, u1.z, u1.w};
            unsigned hw_[4], lw_[4];
            #pragma unroll
            for (int w = 0; w < 4; w++) {
                unsigned short h0 = bf16_rne(v[2 * w]);
                unsigned short h1 = bf16_rne(v[2 * w + 1]);
                unsigned short l0 = bf16_rne(v[2 * w] - bf16_to_f(h0));
                unsigned short l1 = bf16_rne(v[2 * w + 1] - bf16_to_f(h1));
                hw_[w] = (unsigned)h0 | ((unsigned)h1 << 16);
                lw_[w] = (unsigned)l0 | ((unsigned)l1 << 16);
            }
            xhi[s][kt] = make_uint4(hw_[0], hw_[1], hw_[2], hw_[3]);
            xlo[s][kt] = make_uint4(lw_[0], lw_[1], lw_[2], lw_[3]);
        }
    }

    f32x4 oacc[2] = {{0, 0, 0, 0}, {0, 0, 0, 0}};
    unsigned* hw = hbuf + wid * (2 * 16 * 36);

    #pragma unroll
    for (int pp = 0; pp < 4; pp++) {
        // ---- GEMM1: 4 ntiles, both strips, hi+lo passes
        f32x4 acc[2][4];
        #pragma unroll
        for (int n4 = 0; n4 < 4; n4++) {
            float bias = b1s[(4 * pp + n4) * 16 + c];
            acc[0][n4] = (f32x4){bias, bias, bias, bias};
            acc[1][n4] = acc[0][n4];
        }
        #pragma unroll
        for (int kt = 0; kt < 2; kt++) {
            bf16x8 wv[4];
            #pragma unroll
            for (int n4 = 0; n4 < 4; n4++) {
                uint4 wraw = *(const uint4*)(w1f + (((4 * pp + n4) * 2 + kt) * 64 + lane) * 8);
                wv[n4] = __builtin_bit_cast(bf16x8, wraw);
            }
            #pragma unroll
            for (int s = 0; s < 2; s++) {
                bf16x8 ah = __builtin_bit_cast(bf16x8, xhi[s][kt]);
                bf16x8 al = __builtin_bit_cast(bf16x8, xlo[s][kt]);
                #pragma unroll
                for (int n4 = 0; n4 < 4; n4++) {
                    acc[s][n4] = __builtin_amdgcn_mfma_f32_16x16x32_bf16(ah, wv[n4], acc[s][n4], 0, 0, 0);
                    acc[s][n4] = __builtin_amdgcn_mfma_f32_16x16x32_bf16(al, wv[n4], acc[s][n4], 0, 0, 0);
                }
            }
        }
        // ---- tanh + pack (k' = 4c + nt4) + b64 write to wave-private h chunk
        #pragma unroll
        for (int s = 0; s < 2; s++) {
            #pragma unroll
            for (int r = 0; r < 4; r++) {
                unsigned short hh[4];
                #pragma unroll
                for (int n4 = 0; n4 < 4; n4++) hh[n4] = bf16_rne(tanh_fast(acc[s][n4][r]));
                uint2 wp;
                wp.x = (unsigned)hh[0] | ((unsigned)hh[1] << 16);
                wp.y = (unsigned)hh[2] | ((unsigned)hh[3] << 16);
                *(uint2*)(hw + (s * 16 + 4 * q + r) * 36 + 2 * c) = wp;
            }
        }
        // ---- GEMM2: 2 ktiles of this pp-chunk
        #pragma unroll
        for (int tt = 0; tt < 2; tt++) {
            uint4 w2raw = *(const uint4*)(w2f + ((2 * pp + tt) * 64 + lane) * 8);
            bf16x8 bw2 = __builtin_bit_cast(bf16x8, w2raw);
            #pragma unroll
            for (int s = 0; s < 2; s++) {
                uint4 hraw = *(const uint4*)(hw + (s * 16 + c) * 36 + tt * 16 + 4 * q);
                bf16x8 ha = __builtin_bit_cast(bf16x8, hraw);
                oacc[s] = __builtin_amdgcn_mfma_f32_16x16x32_bf16(ha, bw2, oacc[s], 0, 0, 0);
            }
        }
    }
    // ---- store (C layout: row = 4q+r, col = c) + b2
    float b2v = b2[c];
    #pragma unroll
    for (int s = 0; s < 2; s++) {
        #pragma unroll
        for (int r = 0; r < 4; r++) {
            long row = rowbase + 16 * s + 4 * q + r;
            if (row < B) out[row * 16 + c] = oacc[s][r] + b2v;
        }
    }
}

extern "C" void kernel_launch(void* const* d_in, const int* in_sizes, int n_in,
                              void* d_out, int out_size, void* d_ws, size_t ws_size,
                              hipStream_t stream) {
    const float* x  = (const float*)d_in[0];
    const float* A  = (const float*)d_in[1];
    const float* W1 = (const float*)d_in[2];
    const float* b1 = (const float*)d_in[3];
    const float* W2 = (const float*)d_in[4];
    const float* b2 = (const float*)d_in[5];
    float* out = (float*)d_out;
    unsigned short* ws = (unsigned short*)d_ws;  // 40KB fragment area

    const int B = in_sizes[0] / 64;

    ode_precompute<<<1, 1024, 0, stream>>>(A, W1, W2, ws);
    const int grid = (B + 255) / 256;
    ode_main<<<grid, 512, 0, stream>>>(x, ws, b1, b2, out, B);
}

// Round 3
// 183.429 us; speedup vs baseline: 3.3912x; 1.4002x over previous
//
#include <hip/hip_runtime.h>

typedef float f32x4 __attribute__((ext_vector_type(4)));
typedef __bf16 bf16x8 __attribute__((ext_vector_type(8)));
typedef __bf16 bf16x2 __attribute__((ext_vector_type(2)));

__device__ __forceinline__ unsigned short bf16_bits(float f) {
    return __builtin_bit_cast(unsigned short, (__bf16)f);
}
__device__ __forceinline__ unsigned pk2(float a, float b) {
    bf16x2 t; t[0] = (__bf16)a; t[1] = (__bf16)b;
    return __builtin_bit_cast(unsigned, t);
}
__device__ __forceinline__ float tanh_fast(float v) {
    // tanh(v) = 1 - 2/(e^{2v}+1); handles +/-inf correctly via rcp
    float e = __expf(2.0f * v);
    float r = __builtin_amdgcn_rcpf(e + 1.0f);
    return 1.0f - 2.0f * r;
}

#define LDT 68

// ---------------------------------------------------------------------------
// Precompute: T = I + 0.02A; M = T^50 (7 LDS matmuls, fp32); then write
//   ws[0      .. 16383] : W1p = M@W1 as GEMM1 B-fragments (bf16)
//   ws[16384 .. 20479] : W2 as GEMM2 B-fragments (bf16) under k-permutation
// 1 block, 1024 threads.
// ---------------------------------------------------------------------------
__global__ __launch_bounds__(1024) void ode_precompute(
        const float* __restrict__ A, const float* __restrict__ W1,
        const float* __restrict__ W2, unsigned short* __restrict__ ws) {
    __shared__ float Ts[64 * LDT];
    __shared__ float Za[64 * LDT];
    __shared__ float Zb[64 * LDT];
    const int t = threadIdx.x;

    for (int i = t; i < 4096; i += 1024) {
        int r = i >> 6, c = i & 63;
        float v = 0.02f * A[i] + ((r == c) ? 1.0f : 0.0f);
        Ts[r * LDT + c] = v;
        Za[r * LDT + c] = v;
    }
    __syncthreads();

    const int r0 = (t >> 5) * 2;
    const int c0 = (t & 31) * 2;
    auto mm = [&](const float* X, const float* Y, float* Z) {
        float a00 = 0, a01 = 0, a10 = 0, a11 = 0;
        #pragma unroll 8
        for (int k = 0; k < 64; k++) {
            float x0 = X[r0 * LDT + k], x1 = X[(r0 + 1) * LDT + k];
            float y0 = Y[k * LDT + c0], y1 = Y[k * LDT + c0 + 1];
            a00 = fmaf(x0, y0, a00); a01 = fmaf(x0, y1, a01);
            a10 = fmaf(x1, y0, a10); a11 = fmaf(x1, y1, a11);
        }
        Z[r0 * LDT + c0] = a00;       Z[r0 * LDT + c0 + 1] = a01;
        Z[(r0 + 1) * LDT + c0] = a10; Z[(r0 + 1) * LDT + c0 + 1] = a11;
        __syncthreads();
    };
    // 50 = 0b110010 -> sq, *T, sq, sq, sq, *T, sq  (result in Zb)
    mm(Za, Za, Zb); mm(Zb, Ts, Za); mm(Za, Za, Zb); mm(Zb, Zb, Za);
    mm(Za, Za, Zb); mm(Zb, Ts, Za); mm(Za, Za, Zb);

    // W1p: thread (k = t>>4, jb = t&15) computes row k, cols 16*jb .. 16*jb+15
    {
        const int k = t >> 4;
        const int jb = t & 15;
        float acc[16];
        #pragma unroll
        for (int u = 0; u < 16; u++) acc[u] = 0.0f;
        const float* trow = Zb + k * LDT;
        for (int d = 0; d < 64; d++) {
            float a = trow[d];
            const float4* wr = (const float4*)(W1 + d * 256 + jb * 16);
            float4 w0 = wr[0], w1v = wr[1], w2v = wr[2], w3v = wr[3];
            acc[0]  = fmaf(a, w0.x,  acc[0]);  acc[1]  = fmaf(a, w0.y,  acc[1]);
            acc[2]  = fmaf(a, w0.z,  acc[2]);  acc[3]  = fmaf(a, w0.w,  acc[3]);
            acc[4]  = fmaf(a, w1v.x, acc[4]);  acc[5]  = fmaf(a, w1v.y, acc[5]);
            acc[6]  = fmaf(a, w1v.z, acc[6]);  acc[7]  = fmaf(a, w1v.w, acc[7]);
            acc[8]  = fmaf(a, w2v.x, acc[8]);  acc[9]  = fmaf(a, w2v.y, acc[9]);
            acc[10] = fmaf(a, w2v.z, acc[10]); acc[11] = fmaf(a, w2v.w, acc[11]);
            acc[12] = fmaf(a, w3v.x, acc[12]); acc[13] = fmaf(a, w3v.y, acc[13]);
            acc[14] = fmaf(a, w3v.z, acc[14]); acc[15] = fmaf(a, w3v.w, acc[15]);
        }
        const int kt = k >> 5, qq = (k >> 3) & 3, jj = k & 7;
        #pragma unroll
        for (int u = 0; u < 16; u++)
            ws[(((jb * 2 + kt) * 64) + qq * 16 + u) * 8 + jj] = bf16_bits(acc[u]);
    }
    // W2 fragments (4096 elems, 4 per thread); k' = 64pp + 4c + nt4
    #pragma unroll
    for (int e = 0; e < 4; e++) {
        int f = t * 4 + e;
        int kt2 = f >> 9, l = (f >> 3) & 63, j2 = f & 7;
        int kp = 32 * kt2 + 8 * (l >> 4) + j2;
        int row = 64 * (kp >> 6) + 16 * (kp & 3) + ((kp >> 2) & 15);
        ws[16384 + f] = bf16_bits(W2[row * 16 + (l & 15)]);
    }
}

// ---------------------------------------------------------------------------
// Main: out = tanh(x @ W1p + b1) @ W2 + b2, MFMA bf16 (single bf16 x).
// 512 threads (8 waves), 32 rows/wave, 256 rows/block. h in wave-private LDS.
// Coalesced float4 epilogue via LDS transpose (stride 18 f32, conflict-free).
// ---------------------------------------------------------------------------
__global__ __launch_bounds__(512, 4) void ode_main(
        const float* __restrict__ x, const unsigned short* __restrict__ wsfrag,
        const float* __restrict__ b1, const float* __restrict__ b2,
        float* __restrict__ out, int B) {
    __shared__ unsigned short w1f[16384];       // 32KB
    __shared__ unsigned short w2f[4096];        // 8KB
    __shared__ float b1s[256];                  // 1KB
    __shared__ unsigned hbuf[8 * 2 * 16 * 36];  // 36KB (wave-private chunks)
    const int t = threadIdx.x;
    {
        const uint4* src = (const uint4*)wsfrag;  // 2560 uint4
        uint4* d1 = (uint4*)w1f;
        #pragma unroll
        for (int i = 0; i < 4; i++) d1[t + 512 * i] = src[t + 512 * i];
        ((uint4*)w2f)[t] = src[2048 + t];
        if (t < 64) ((float4*)b1s)[t] = ((const float4*)b1)[t];
    }
    __syncthreads();

    const int wid = t >> 6, lane = t & 63;
    const int q = lane >> 4, c = lane & 15;
    const long rowbase = (long)blockIdx.x * 256 + wid * 32;

    // ---- load x (2 strips x 2 ktiles x 8 floats), single bf16 conversion
    bf16x8 xb[2][2];
    #pragma unroll
    for (int s = 0; s < 2; s++) {
        long row = rowbase + 16 * s + c;
        const float* xp = x + ((row < B) ? row : 0) * 64;
        #pragma unroll
        for (int kt = 0; kt < 2; kt++) {
            float4 u0 = *(const float4*)(xp + kt * 32 + q * 8);
            float4 u1 = *(const float4*)(xp + kt * 32 + q * 8 + 4);
            bf16x8 cv;
            cv[0] = (__bf16)u0.x; cv[1] = (__bf16)u0.y;
            cv[2] = (__bf16)u0.z; cv[3] = (__bf16)u0.w;
            cv[4] = (__bf16)u1.x; cv[5] = (__bf16)u1.y;
            cv[6] = (__bf16)u1.z; cv[7] = (__bf16)u1.w;
            xb[s][kt] = cv;
        }
    }

    // bias values for this lane's column across all 16 ntiles
    float biasv[16];
    #pragma unroll
    for (int n = 0; n < 16; n++) biasv[n] = b1s[n * 16 + c];

    f32x4 oacc[2] = {{0, 0, 0, 0}, {0, 0, 0, 0}};
    unsigned* hw = hbuf + wid * (2 * 16 * 36);

    #pragma unroll
    for (int pp = 0; pp < 4; pp++) {
        // ---- GEMM1: 4 ntiles x 2 strips
        f32x4 acc[2][4];
        #pragma unroll
        for (int n4 = 0; n4 < 4; n4++) {
            float bias = biasv[4 * pp + n4];
            acc[0][n4] = (f32x4){bias, bias, bias, bias};
            acc[1][n4] = acc[0][n4];
        }
        #pragma unroll
        for (int kt = 0; kt < 2; kt++) {
            bf16x8 wv[4];
            #pragma unroll
            for (int n4 = 0; n4 < 4; n4++) {
                uint4 wraw = *(const uint4*)(w1f + (((4 * pp + n4) * 2 + kt) * 64 + lane) * 8);
                wv[n4] = __builtin_bit_cast(bf16x8, wraw);
            }
            #pragma unroll
            for (int s = 0; s < 2; s++) {
                #pragma unroll
                for (int n4 = 0; n4 < 4; n4++)
                    acc[s][n4] = __builtin_amdgcn_mfma_f32_16x16x32_bf16(xb[s][kt], wv[n4], acc[s][n4], 0, 0, 0);
            }
        }
        // ---- tanh + pack (k' = 4c + nt4) + b64 write to wave-private h chunk
        #pragma unroll
        for (int s = 0; s < 2; s++) {
            #pragma unroll
            for (int r = 0; r < 4; r++) {
                float h0 = tanh_fast(acc[s][0][r]);
                float h1 = tanh_fast(acc[s][1][r]);
                float h2 = tanh_fast(acc[s][2][r]);
                float h3 = tanh_fast(acc[s][3][r]);
                uint2 wp;
                wp.x = pk2(h0, h1);
                wp.y = pk2(h2, h3);
                *(uint2*)(hw + (s * 16 + 4 * q + r) * 36 + 2 * c) = wp;
            }
        }
        // ---- GEMM2: 2 ktiles of this pp-chunk
        #pragma unroll
        for (int tt = 0; tt < 2; tt++) {
            uint4 w2raw = *(const uint4*)(w2f + ((2 * pp + tt) * 64 + lane) * 8);
            bf16x8 bw2 = __builtin_bit_cast(bf16x8, w2raw);
            #pragma unroll
            for (int s = 0; s < 2; s++) {
                uint4 hraw = *(const uint4*)(hw + (s * 16 + c) * 36 + tt * 16 + 4 * q);
                bf16x8 ha = __builtin_bit_cast(bf16x8, hraw);
                oacc[s] = __builtin_amdgcn_mfma_f32_16x16x32_bf16(ha, bw2, oacc[s], 0, 0, 0);
            }
        }
    }
    // ---- epilogue: transpose via wave-private LDS (stride 18), float4 store
    float b2v = b2[c];
    float* hwf = (float*)hw;
    #pragma unroll
    for (int s = 0; s < 2; s++) {
        #pragma unroll
        for (int r = 0; r < 4; r++)
            hwf[(4 * q + r) * 18 + c] = oacc[s][r] + b2v;
        long row = rowbase + 16 * s + (lane >> 2);
        float4 val = *(const float4*)(hwf + (lane >> 2) * 18 + (lane & 3) * 4);
        if (row < B) *(float4*)(out + row * 16 + (lane & 3) * 4) = val;
    }
}

extern "C" void kernel_launch(void* const* d_in, const int* in_sizes, int n_in,
                              void* d_out, int out_size, void* d_ws, size_t ws_size,
                              hipStream_t stream) {
    const float* x  = (const float*)d_in[0];
    const float* A  = (const float*)d_in[1];
    const float* W1 = (const float*)d_in[2];
    const float* b1 = (const float*)d_in[3];
    const float* W2 = (const float*)d_in[4];
    const float* b2 = (const float*)d_in[5];
    float* out = (float*)d_out;
    unsigned short* ws = (unsigned short*)d_ws;  // 40KB fragment area

    const int B = in_sizes[0] / 64;

    ode_precompute<<<1, 1024, 0, stream>>>(A, W1, W2, ws);
    const int grid = (B + 255) / 256;
    ode_main<<<grid, 512, 0, stream>>>(x, ws, b1, b2, out, B);
}